// Round 9
// baseline (476.103 us; speedup 1.0000x reference)
//
#include <hip/hip_runtime.h>
#include <hip/hip_bf16.h>
#include <cstdint>
#include <cstddef>

typedef __bf16 bf16_t;
typedef bf16_t bf16x8 __attribute__((ext_vector_type(8)));
typedef float f32x16 __attribute__((ext_vector_type(16)));

#define BN_EPS 1e-5f

// r14 (174us): per-block fusion. r15 (220): h1 LDS-only, traffic 322->112MB,
// but latency-bound. r17 (CLIFF): unified VGPR+AGPR budget is 512/waves-per-EU;
// exceeding it spills catastrophically. r18 (214): fits, 46% occupancy, but
// allocator chose 64 VGPR -> zero ILP; gemm2 chain (2 L2 gathers + 2 ds_reads
// -> 8 MFMA) serialized per wave; MfmaUtil stuck at 20%.
// r19: switch both GEMMs to v_mfma_f32_32x32x16_bf16 — 2x FLOP per instruction
// at identical per-lane operand bytes -> fragment/LDS traffic halves and each
// latency stall buys 2x math (1.25x FLOP/cyc pipe rate). 16 waves x 32-col
// tiles; h1 chunks of 512 cols; acc1=acc2=32 regs -> ~110 unified, fits 128
// with room for depth-2 staging (gemm1) and rolling W2T prefetch (gemm2).
// C/D layout (m74/m101 verified): col=lane&31, row=(reg&3)+8*(reg>>2)+4*(l>>5).
__device__ __forceinline__ void async_load16(const bf16_t* g, bf16_t* lds) {
  __builtin_amdgcn_global_load_lds(
      (__attribute__((address_space(1))) uint32_t*)(g),
      (__attribute__((address_space(3))) uint32_t*)(lds),
      16, 0, 0);
}

// ---- Weight prep (transposes + BN folds), tiny ------------------------------
__global__ void prep_weights_kernel(const float* __restrict__ W1, const float* __restrict__ W2,
                                    const float* b1, const float* g1, const float* be1,
                                    const float* m1, const float* v1,
                                    const float* b2, const float* g2, const float* be2,
                                    const float* m2, const float* v2,
                                    bf16_t* __restrict__ W1T, bf16_t* __restrict__ W2T,
                                    float* s1, float* t1, float* s2, float* t2,
                                    float* w1last) {
  const int b = blockIdx.x;
  if (b < 192) {
    const float* src;
    bf16_t* dst;
    int R, C, bx, by;
    if (b < 64) { src = W1; dst = W1T; R = 256; C = 1024; bx = b & 15; by = b >> 4; }
    else        { src = W2; dst = W2T; R = 1024; C = 512; bx = (b - 64) & 7; by = (b - 64) >> 3; }
    __shared__ bf16_t tile[64][66];
    const int r0 = by * 64, c0 = bx * 64;
    const int tc = threadIdx.x & 63;
    const int tr4 = threadIdx.x >> 6;
#pragma unroll
    for (int i = 0; i < 16; ++i) {
      int r = i * 4 + tr4;
      tile[r][tc] = (bf16_t)src[(size_t)(r0 + r) * C + c0 + tc];  // coalesced read
    }
    __syncthreads();
#pragma unroll
    for (int i = 0; i < 16; ++i) {
      int rr = i * 4 + tr4;
      dst[(size_t)(c0 + rr) * R + r0 + tc] = tile[tc][rr];  // coalesced write
    }
  } else {
    for (int i = threadIdx.x; i < 1024; i += 256) {
      float s = g1[i] * rsqrtf(v1[i] + BN_EPS);
      s1[i] = s;
      t1[i] = be1[i] - m1[i] * s + b1[i] * s;  // bn(z+b1) = z*s + t
      w1last[i] = W1[256 * 1024 + i];          // conv-feature row (coalesced)
      if (i < 512) {
        float s2v = g2[i] * rsqrtf(v2[i] + BN_EPS);
        s2[i] = s2v;
        t2[i] = be2[i] - m2[i] * s2v + b2[i] * s2v;
      }
    }
  }
}

// ---- Fully-fused per-block MLP: 64 rows, 16 waves, 32x32 MFMA, h1 LDS-only --
// LDS 128 KB: As[64][256] 32K (chunk-swizzled) | h1c[64][512] 64K
// (chunk-swizzled; convs[64] overlays pre-use) | B1s 16 waves x 2 bufs x 1KB
// = 32K (outW[16][64] overlays at the end).
__global__ __launch_bounds__(1024, 4) void fused_mlp(
    const float* __restrict__ x,
    const bf16_t* __restrict__ W1T, const bf16_t* __restrict__ W2T,
    const float* __restrict__ s1, const float* __restrict__ t1,
    const float* __restrict__ w1last,
    const float* __restrict__ s2, const float* __restrict__ t2,
    const float* __restrict__ W3, const float* __restrict__ b3,
    float* __restrict__ out) {
  __shared__ __align__(16) unsigned char smem[131072];
  const int tid = threadIdx.x;
  const int lane = tid & 63;
  const int w = tid >> 6;          // 0..15
  const int l31 = lane & 31;
  const int half = lane >> 5;      // 0..1
  const int mTile = blockIdx.x * 64;

  bf16_t* As = (bf16_t*)smem;                 // [64][256], chunk-swizzled
  bf16_t* h1c = (bf16_t*)(smem + 32768);      // [64][512], chunk-swizzled
  float* convs = (float*)(smem + 32768);      // overlay (pre-h1c use)
  bf16_t* B1s = (bf16_t*)(smem + 98304);      // [16 waves][2 bufs][512 bf16]
  float* outW = (float*)(smem + 98304);       // overlay (post-B1s use)

  // ---- prologue: x fp32 -> bf16 into As (swizzled), per-row conv ----------
  {
    const int rsub = lane >> 5;     // 0..1
    const int cc = lane & 31;       // 8-elem chunk within row
#pragma unroll
    for (int i = 0; i < 2; ++i) {
      int row = w * 4 + i * 2 + rsub;
      const float* gx = x + (size_t)(mTile + row) * 256 + cc * 8;
      const float4 a = *(const float4*)gx;
      const float4 bq = *(const float4*)(gx + 4);
      float s = a.x + a.y + a.z + a.w + bq.x + bq.y + bq.z + bq.w;
      bf16x8 v = {(bf16_t)a.x, (bf16_t)a.y, (bf16_t)a.z, (bf16_t)a.w,
                  (bf16_t)bq.x, (bf16_t)bq.y, (bf16_t)bq.z, (bf16_t)bq.w};
      *(bf16x8*)(As + row * 256 + (cc ^ (row & 7)) * 8) = v;
#pragma unroll
      for (int m = 1; m <= 16; m <<= 1) s += __shfl_xor(s, m);  // 32-lane groups
      if (cc == 0) convs[row] = (s > 0.0f) ? 1.0f : 0.0f;  // mean>0 <=> sum>0
    }
  }
  __syncthreads();  // As + convs visible

  // Conv bitmask for the 32 rows this lane's C-fragments touch (2 tiles x 16).
  // Row of reg r, tile t: t*32 + (r&3) + 8*(r>>2) + 4*half.
  unsigned cmask = 0;
#pragma unroll
  for (int t = 0; t < 2; ++t)
#pragma unroll
    for (int q = 0; q < 4; ++q)
#pragma unroll
      for (int m = 0; m < 4; ++m)
        if (convs[t * 32 + q * 8 + m + 4 * half] > 0.5f)
          cmask |= 1u << (t * 16 + q * 4 + m);
  // convs-read vs h1c-write WAR sealed by chunk-0's pre-epilogue barrier.

  bf16_t* B1w = B1s + w * 1024;   // wave-private: 2 bufs x 512 bf16 (1 KB each)
  // B1 stage: dest byte lane*16 holds (col = lane>>1, khalf = lane&1) — lane
  // pairs read 32B contiguous per W1T row (merge-friendly). Compute read for
  // lane l (col=l31, khalf=half) is byte (l31*2+half)*16: unique slot per lane.
  const int brd = (l31 * 2 + half) * 8;   // element offset of B read

  // Persistent gemm2 accumulators: wave owns N-cols [w*32, w*32+32).
  f32x16 acc2[2];
#pragma unroll
  for (int t = 0; t < 2; ++t)
#pragma unroll
    for (int i = 0; i < 16; ++i) acc2[t][i] = 0.f;

  for (int c = 0; c < 2; ++c) {
    // ---- gemm1: wave w owns cols c*512 + w*32 .. +31; K=256 = 16 steps ----
    const int colbase = c * 512 + w * 32;
    f32x16 acc1[2];
#pragma unroll
    for (int t = 0; t < 2; ++t)
#pragma unroll
      for (int i = 0; i < 16; ++i) acc1[t][i] = 0.f;

    const bf16_t* gB1 = W1T + (size_t)(colbase + (lane >> 1)) * 256 + (lane & 1) * 8;

    // Depth-2 ping-pong prologue: ks=0 -> buf0, ks=1 -> buf1.
    async_load16(gB1, B1w + lane * 8);
    async_load16(gB1 + 16, B1w + 512 + lane * 8);

#pragma unroll
    for (int ks = 0; ks < 16; ++ks) {
      if (ks < 15) asm volatile("s_waitcnt vmcnt(1)" ::: "memory");
      else         asm volatile("s_waitcnt vmcnt(0)" ::: "memory");
      __builtin_amdgcn_sched_barrier(0);  // rule #18

      bf16x8 bfr = *(const bf16x8*)(B1w + (ks & 1) * 512 + brd);
      bf16x8 af0 = *(const bf16x8*)(As + l31 * 256 + ((ks * 2 + half) ^ (l31 & 7)) * 8);
      bf16x8 af1 = *(const bf16x8*)(As + (l31 + 32) * 256 + ((ks * 2 + half) ^ (l31 & 7)) * 8);

      asm volatile("s_waitcnt lgkmcnt(0)" ::: "memory");  // frags in regs
      __builtin_amdgcn_sched_barrier(0);  // rule #18
      if (ks < 14)
        async_load16(gB1 + (ks + 2) * 16, B1w + (ks & 1) * 512 + lane * 8);

      __builtin_amdgcn_s_setprio(1);
      acc1[0] = __builtin_amdgcn_mfma_f32_32x32x16_bf16(af0, bfr, acc1[0], 0, 0, 0);
      acc1[1] = __builtin_amdgcn_mfma_f32_32x32x16_bf16(af1, bfr, acc1[1], 0, 0, 0);
      __builtin_amdgcn_s_setprio(0);
    }

    __syncthreads();  // WAR: all waves done reading h1c (chunk c-1) / convs

    // Epilogue: conv rank-1 + BN1 + ReLU -> h1c (LDS, swizzled)
    {
      const int ccol = colbase + l31;      // absolute W1 col (one per lane)
      const float sc1 = s1[ccol];
      const float tc1 = t1[ccol];
      const float wl1 = w1last[ccol];
      const int cc2 = w * 4 + (l31 >> 3);  // chunk index of this lane's col
      const int j = lane & 7;
#pragma unroll
      for (int t = 0; t < 2; ++t)
#pragma unroll
        for (int r = 0; r < 16; ++r) {
          const int row = (r & 3) + 8 * (r >> 2) + 4 * half + t * 32;
          const float cfv = ((cmask >> (t * 16 + (r >> 2) * 4 + (r & 3))) & 1u) ? 1.0f : 0.0f;
          float z = acc1[t][r] + cfv * wl1;
          z = fmaxf(z * sc1 + tc1, 0.f);
          h1c[row * 512 + (cc2 ^ (row & 7)) * 8 + j] = (bf16_t)z;
        }
    }
    __syncthreads();  // h1c chunk complete + visible

    // ---- gemm2 partial: K-range [c*512,(c+1)*512) = 32 steps of K=16.
    // B reg-direct from L2 (disjoint 32-col slice per wave), rolling depth-2
    // prefetch; A from h1c LDS. No barriers — compiler pipelines freely.
    const bf16_t* gB2 = W2T + (size_t)(w * 32 + l31) * 1024 + c * 512 + half * 8;
    bf16x8 bcur = *(const bf16x8*)(gB2);
#pragma unroll
    for (int s = 0; s < 32; ++s) {
      bf16x8 bnxt;
      if (s < 31) bnxt = *(const bf16x8*)(gB2 + (s + 1) * 16);
      bf16x8 a0 = *(const bf16x8*)(h1c + l31 * 512 + ((s * 2 + half) ^ (l31 & 7)) * 8);
      bf16x8 a1 = *(const bf16x8*)(h1c + (l31 + 32) * 512 + ((s * 2 + half) ^ (l31 & 7)) * 8);
      __builtin_amdgcn_s_setprio(1);
      acc2[0] = __builtin_amdgcn_mfma_f32_32x32x16_bf16(a0, bcur, acc2[0], 0, 0, 0);
      acc2[1] = __builtin_amdgcn_mfma_f32_32x32x16_bf16(a1, bcur, acc2[1], 0, 0, 0);
      __builtin_amdgcn_s_setprio(0);
      if (s < 31) bcur = bnxt;
    }
  }

  // ---- final epilogue: BN2 + ReLU + W3-dot; reduce over the wave's 32 cols --
  {
    const int ncol = w * 32 + l31;
    const float sc = s2[ncol];
    const float tcs = t2[ncol];
    const float w3c = W3[ncol];
#pragma unroll
    for (int t = 0; t < 2; ++t)
#pragma unroll
      for (int r = 0; r < 16; ++r) {
        float z = fmaxf(acc2[t][r] * sc + tcs, 0.f) * w3c;
#pragma unroll
        for (int m = 1; m <= 16; m <<= 1) z += __shfl_xor(z, m);  // 32-col sum
        if (l31 == 0)
          outW[w * 64 + t * 32 + (r & 3) + 8 * (r >> 2) + 4 * half] = z;
      }
  }
  // B1s fully retired: last staging self-drained (ks=15 vmcnt(0)) and all
  // waves passed chunk-1's h1c barrier before any outW write... (outW
  // overlays only B1s; ordering via each wave's own program order + barrier).
  __syncthreads();
  if (tid < 64) {
    float z = b3[0];
#pragma unroll
    for (int k = 0; k < 16; ++k) z += outW[k * 64 + tid];
    out[mTile + tid] = 1.0f / (1.0f + expf(-z));
  }
}

extern "C" void kernel_launch(void* const* d_in, const int* in_sizes, int n_in,
                              void* d_out, int out_size, void* d_ws, size_t ws_size,
                              hipStream_t stream) {
  const float* x = (const float*)d_in[0];
  const float* W1 = (const float*)d_in[1];
  const float* b1 = (const float*)d_in[2];
  const float* g1 = (const float*)d_in[3];
  const float* be1 = (const float*)d_in[4];
  const float* m1 = (const float*)d_in[5];
  const float* v1 = (const float*)d_in[6];
  const float* W2 = (const float*)d_in[7];
  const float* b2 = (const float*)d_in[8];
  const float* g2 = (const float*)d_in[9];
  const float* be2 = (const float*)d_in[10];
  const float* m2 = (const float*)d_in[11];
  const float* v2 = (const float*)d_in[12];
  const float* W3 = (const float*)d_in[13];
  const float* b3 = (const float*)d_in[14];
  float* out = (float*)d_out;

  char* p = (char*)d_ws;
  bf16_t* h1 = (bf16_t*)p;       p += (size_t)65536 * 1024 * 2;  // unused (layout kept)
  float* partials = (float*)p;   p += (size_t)4 * 65536 * 4;     // unused
  bf16_t* W1T = (bf16_t*)p;      p += (size_t)1024 * 256 * 2;
  bf16_t* W2T = (bf16_t*)p;      p += (size_t)512 * 1024 * 2;
  float* w1last = (float*)p;     p += 1024 * 4;
  float* s1 = (float*)p;         p += 1024 * 4;
  float* t1 = (float*)p;         p += 1024 * 4;
  float* s2 = (float*)p;         p += 512 * 4;
  float* t2 = (float*)p;         p += 512 * 4;
  (void)h1;
  (void)partials;

  prep_weights_kernel<<<193, 256, 0, stream>>>(W1, W2, b1, g1, be1, m1, v1,
                                               b2, g2, be2, m2, v2,
                                               W1T, W2T, s1, t1, s2, t2, w1last);

  fused_mlp<<<1024, 1024, 0, stream>>>(x, W1T, W2T, s1, t1, w1last,
                                       s2, t2, W3, b3, out);
}